// Round 1
// baseline (93.279 us; speedup 1.0000x reference)
//
#include <hip/hip_runtime.h>

typedef __attribute__((ext_vector_type(8))) short svec8;
typedef __attribute__((ext_vector_type(4))) float fvec4;

#define NB    4096
#define NN    6
#define FF    512
#define CC    256
#define KFULL 1024
#define MROWS (NB*NN)                 // 24576
#define AD_HALF ((size_t)MROWS*CC)    // 6291456 elements
#define NTOT  (NB*NN*NN)              // 147456

__device__ __forceinline__ unsigned short f2bf(float f) {
    unsigned u = __float_as_uint(f);
    u += 0x7FFFu + ((u >> 16) & 1u);   // round-to-nearest-even
    return (unsigned short)(u >> 16);
}
__device__ __forceinline__ float bf2f(unsigned short h) {
    return __uint_as_float(((unsigned)h) << 16);
}

// ---------------- kernel 0: conv_w fp32 -> bf16 ----------------
__global__ __launch_bounds__(256) void k_wconv(const float* __restrict__ w,
                                               unsigned short* __restrict__ wbf) {
    int i = blockIdx.x * 256 + threadIdx.x;   // grid 1024 -> 262144
    wbf[i] = f2bf(w[i]);
}

// ---------------- kernel 1: two GEMMs (A and D halves) ----------------
// A[m,c] = dot(x[b,0,jn,:], W[c,0:512]),  D[m,c] = dot(x[b,1,jn,:], W[c,512:1024])
// m = b*6+jn. Tile: BM=64 rows x BN=256 cols, BK=64. 256 threads (4 waves),
// wave w covers cols [w*64, w*64+64). bf16 MFMA 16x16x32, XOR-swizzled LDS.
__global__ __launch_bounds__(256) void k_gemm(const float* __restrict__ x,
                                              const unsigned short* __restrict__ wbf,
                                              unsigned short* __restrict__ AD) {
    __shared__ __align__(16) char lds[40960];   // A: [64][64]bf16=8KB, B: [256][64]bf16=32KB
    const int tid = threadIdx.x;
    const int s = blockIdx.x & 1;
    const int mtile = blockIdx.x >> 1;

    // --- staging addresses ---
    const int slot = tid & 7;        // 16B slot within a 64-elem (128B) row
    const int arow0 = tid >> 3;      // rows 0..31 (i=0), +32 (i=1)
    const float* aptr[2];
#pragma unroll
    for (int i = 0; i < 2; ++i) {
        int row = arow0 + 32 * i;
        int m = mtile * 64 + row;
        int b = m / 6;
        int jn = m - b * 6;
        aptr[i] = x + ((size_t)((b * 2 + s) * 6 + jn)) * FF + slot * 8;
    }
    const int a_lds0 = arow0 * 128 + ((slot * 16) ^ ((arow0 & 7) << 4));
    const unsigned short* bptr0 = wbf + (size_t)(tid >> 3) * KFULL + s * FF + slot * 8;
    const int b_lds0 = 8192 + (tid >> 3) * 128 + ((slot * 16) ^ (((tid >> 3) & 7) << 4));

    // --- fragment LDS offsets (tile-invariant) ---
    const int l = tid & 63;
    const int wv = tid >> 6;
    const int lrow = l & 15;
    const int lk = l >> 4;
    int abase[2], bbase[2];
#pragma unroll
    for (int ks = 0; ks < 2; ++ks) {
        int kb = ks * 64 + lk * 16;
        int xr = kb ^ ((lrow & 7) << 4);
        abase[ks] = lrow * 128 + xr;
        bbase[ks] = 8192 + (wv * 64 + lrow) * 128 + xr;
    }

    const fvec4 vzero = {0.f, 0.f, 0.f, 0.f};
    fvec4 acc[4][4];
#pragma unroll
    for (int mi = 0; mi < 4; ++mi)
#pragma unroll
        for (int ni = 0; ni < 4; ++ni) acc[mi][ni] = vzero;

    for (int kt = 0; kt < 8; ++kt) {
        const int k0 = kt * 64;
        // stage A (fp32 -> bf16 convert in regs, swizzled ds_write_b128)
#pragma unroll
        for (int i = 0; i < 2; ++i) {
            const float* p = aptr[i] + k0;
            fvec4 lo = *(const fvec4*)p;
            fvec4 hi = *(const fvec4*)(p + 4);
            svec8 v;
            v[0] = (short)f2bf(lo[0]); v[1] = (short)f2bf(lo[1]);
            v[2] = (short)f2bf(lo[2]); v[3] = (short)f2bf(lo[3]);
            v[4] = (short)f2bf(hi[0]); v[5] = (short)f2bf(hi[1]);
            v[6] = (short)f2bf(hi[2]); v[7] = (short)f2bf(hi[3]);
            *(svec8*)(lds + a_lds0 + i * 4096) = v;
        }
        // stage B (bf16 pass-through)
#pragma unroll
        for (int i = 0; i < 8; ++i) {
            svec8 v = *(const svec8*)(bptr0 + (size_t)i * 32 * KFULL + k0);
            *(svec8*)(lds + b_lds0 + i * 4096) = v;
        }
        __syncthreads();
#pragma unroll
        for (int ks = 0; ks < 2; ++ks) {
            svec8 af[4], bfr[4];
#pragma unroll
            for (int mi = 0; mi < 4; ++mi) af[mi] = *(const svec8*)(lds + abase[ks] + mi * 2048);
#pragma unroll
            for (int ni = 0; ni < 4; ++ni) bfr[ni] = *(const svec8*)(lds + bbase[ks] + ni * 2048);
#pragma unroll
            for (int mi = 0; mi < 4; ++mi)
#pragma unroll
                for (int ni = 0; ni < 4; ++ni)
                    acc[mi][ni] = __builtin_amdgcn_mfma_f32_16x16x32_bf16(
                        af[mi], bfr[ni], acc[mi][ni], 0, 0, 0);
        }
        __syncthreads();
    }

    // epilogue: C/D layout col=lane&15, row=(lane>>4)*4+reg
    unsigned short* op = AD + (size_t)s * AD_HALF;
#pragma unroll
    for (int mi = 0; mi < 4; ++mi) {
#pragma unroll
        for (int j = 0; j < 4; ++j) {
            int r = mi * 16 + lk * 4 + j;
            size_t m = (size_t)(mtile * 64 + r);
#pragma unroll
            for (int ni = 0; ni < 4; ++ni) {
                int c = wv * 64 + ni * 16 + lrow;
                op[m * 256 + c] = f2bf(acc[mi][ni][j]);
            }
        }
    }
}

// ---------------- kernel 2: per-channel stats of relu(A+D+bias) ----------------
// For fixed b, the 36 (i,j) cells hit exactly the 36 (j,d) pairs once each.
__global__ __launch_bounds__(256) void k_stats(const unsigned short* __restrict__ AD,
                                               const float* __restrict__ conv_b,
                                               float* __restrict__ stats) {
    const int c = threadIdx.x;
    const float bias = conv_b[c];
    float s = 0.f, s2 = 0.f;
    const int b0 = blockIdx.x * 8;   // grid 512
    for (int bb = 0; bb < 8; ++bb) {
        const size_t base = (size_t)(b0 + bb) * (6 * 256) + c;
        const unsigned short* ga = AD + base;
        const unsigned short* gd = AD + AD_HALF + base;
        float a[6], d[6];
#pragma unroll
        for (int j = 0; j < 6; ++j) { a[j] = bf2f(ga[j * 256]); d[j] = bf2f(gd[j * 256]); }
#pragma unroll
        for (int j = 0; j < 6; ++j) {
            float aj = a[j] + bias;
#pragma unroll
            for (int e = 0; e < 6; ++e) {
                float h = fmaxf(aj + d[e], 0.f);
                s += h;
                s2 = fmaf(h, h, s2);
            }
        }
    }
    atomicAdd(&stats[c], s);
    atomicAdd(&stats[256 + c], s2);
}

// ---------------- kernel 3: normalize + write output ----------------
__global__ __launch_bounds__(256) void k_out(const unsigned short* __restrict__ AD,
                                             const float* __restrict__ conv_b,
                                             const float* __restrict__ gamma,
                                             const float* __restrict__ beta,
                                             const float* __restrict__ stats,
                                             float* __restrict__ out) {
    __shared__ float Al[6][260], Dl[6][260];
    __shared__ float sc[256], sh[256], bi[256];
    const int t = threadIdx.x;
    const int b = blockIdx.x;
    const unsigned short* ga = AD + (size_t)b * 1536;
    const unsigned short* gd = AD + AD_HALF + (size_t)b * 1536;
#pragma unroll
    for (int i = 0; i < 6; ++i) {
        Al[i][t] = bf2f(ga[i * 256 + t]);
        Dl[i][t] = bf2f(gd[i * 256 + t]);
    }
    const float inv_n = 1.0f / (float)NTOT;
    float mean = stats[t] * inv_n;
    float var = fmaf(-mean, mean, stats[256 + t] * inv_n);
    float scale = gamma[t] * rsqrtf(var + 1e-5f);
    sc[t] = scale;
    sh[t] = fmaf(-mean, scale, beta[t]);
    bi[t] = conv_b[t];
    __syncthreads();
    float* ob = out + (size_t)b * 9216;
#pragma unroll
    for (int it = 0; it < 36; ++it) {
        int idx = it * 256 + t;
        int c = idx / 36;
        int r = idx - c * 36;
        int ii = r / 6;
        int j = r - ii * 6;
        int d = j - ii; if (d < 0) d += 6;
        float h = fmaxf(Al[j][c] + Dl[d][c] + bi[c], 0.f);
        ob[idx] = fmaf(h, sc[c], sh[c]);
    }
}

extern "C" void kernel_launch(void* const* d_in, const int* in_sizes, int n_in,
                              void* d_out, int out_size, void* d_ws, size_t ws_size,
                              hipStream_t stream) {
    const float* x      = (const float*)d_in[0];
    const float* conv_w = (const float*)d_in[1];
    const float* conv_b = (const float*)d_in[2];
    const float* gamma  = (const float*)d_in[3];
    const float* beta   = (const float*)d_in[4];
    float* out = (float*)d_out;

    char* ws = (char*)d_ws;
    unsigned short* wbf = (unsigned short*)ws;                       // 512 KB
    unsigned short* AD  = (unsigned short*)(ws + 524288);            // 2*24576*256*2 = 25165824 B
    float* stats        = (float*)(ws + 524288 + 25165824);          // 2 KB

    k_wconv<<<1024, 256, 0, stream>>>(conv_w, wbf);
    k_gemm<<<768, 256, 0, stream>>>(x, wbf, AD);
    hipMemsetAsync(stats, 0, 512 * sizeof(float), stream);
    k_stats<<<512, 256, 0, stream>>>(AD, conv_b, stats);
    k_out<<<4096, 256, 0, stream>>>(AD, conv_b, gamma, beta, stats, out);
}